// Round 7
// baseline (433.597 us; speedup 1.0000x reference)
//
#include <hip/hip_runtime.h>
#include <hip/hip_bf16.h>
#include <stdint.h>

#define B_ 8
#define L_ 8192
#define C_ 512

typedef short bf16x8 __attribute__((ext_vector_type(8)));
typedef float f32x4 __attribute__((ext_vector_type(4)));

#define GAS(p) ((const __attribute__((address_space(1))) void*)(p))
#define LAS(p) ((__attribute__((address_space(3))) void*)(p))

// ------- kernel 1: kv[b][c] = sum_l (k/||k||)*v   AND   qb = bf16(q/||q||) -------
// (unchanged from r4: ~89 us, ~5.3 TB/s effective; near streaming limit)
__global__ __launch_bounds__(256)
void kv_qnorm(const float* __restrict__ kin, const float* __restrict__ vin,
              const float* __restrict__ qin, float* __restrict__ kv,
              __hip_bfloat16* __restrict__ qb) {
    const int bi   = blockIdx.x;
    const int b    = bi >> 8;             // 256 blocks per batch
    const int row0 = (bi & 255) * 32;
    const int lane = threadIdx.x & 63;
    const int wave = threadIdx.x >> 6;

    const f32x4* kb = (const f32x4*)(kin + ((size_t)b * L_ + row0) * C_);
    const f32x4* vb = (const f32x4*)(vin + ((size_t)b * L_ + row0) * C_);

    f32x4 acca = {0.f,0.f,0.f,0.f}, accb = {0.f,0.f,0.f,0.f};

    #pragma unroll 1
    for (int it = 0; it < 2; ++it) {
        const int r0 = wave * 8 + it * 4;
        f32x4 ka[4], kc[4], va[4], vc[4];
        #pragma unroll
        for (int j = 0; j < 4; ++j) {
            const f32x4* krow = kb + (size_t)(r0 + j) * (C_/4);
            ka[j] = __builtin_nontemporal_load(krow + lane);
            kc[j] = __builtin_nontemporal_load(krow + 64 + lane);
        }
        #pragma unroll
        for (int j = 0; j < 4; ++j) {
            const f32x4* vrow = vb + (size_t)(r0 + j) * (C_/4);
            va[j] = __builtin_nontemporal_load(vrow + lane);
            vc[j] = __builtin_nontemporal_load(vrow + 64 + lane);
        }
        float ss[4];
        #pragma unroll
        for (int j = 0; j < 4; ++j)
            ss[j] = ka[j][0]*ka[j][0] + ka[j][1]*ka[j][1] + ka[j][2]*ka[j][2] + ka[j][3]*ka[j][3]
                  + kc[j][0]*kc[j][0] + kc[j][1]*kc[j][1] + kc[j][2]*kc[j][2] + kc[j][3]*kc[j][3];
        #pragma unroll
        for (int m = 32; m >= 1; m >>= 1) {
            #pragma unroll
            for (int j = 0; j < 4; ++j) ss[j] += __shfl_xor(ss[j], m);
        }
        #pragma unroll
        for (int j = 0; j < 4; ++j) {
            const float inv = rsqrtf(ss[j]);
            #pragma unroll
            for (int x = 0; x < 4; ++x) {
                acca[x] += ka[j][x] * inv * va[j][x];
                accb[x] += kc[j][x] * inv * vc[j][x];
            }
        }
    }

    const f32x4* qg = (const f32x4*)(qin + ((size_t)b * L_ + row0) * C_);
    __hip_bfloat16* qbo = qb + ((size_t)b * L_ + row0) * C_;
    #pragma unroll 1
    for (int it = 0; it < 2; ++it) {
        const int r0 = wave * 8 + it * 4;
        f32x4 qa[4], qc[4];
        #pragma unroll
        for (int j = 0; j < 4; ++j) {
            const f32x4* qrow = qg + (size_t)(r0 + j) * (C_/4);
            qa[j] = __builtin_nontemporal_load(qrow + lane);
            qc[j] = __builtin_nontemporal_load(qrow + 64 + lane);
        }
        float ss[4];
        #pragma unroll
        for (int j = 0; j < 4; ++j)
            ss[j] = qa[j][0]*qa[j][0] + qa[j][1]*qa[j][1] + qa[j][2]*qa[j][2] + qa[j][3]*qa[j][3]
                  + qc[j][0]*qc[j][0] + qc[j][1]*qc[j][1] + qc[j][2]*qc[j][2] + qc[j][3]*qc[j][3];
        #pragma unroll
        for (int m = 32; m >= 1; m >>= 1) {
            #pragma unroll
            for (int j = 0; j < 4; ++j) ss[j] += __shfl_xor(ss[j], m);
        }
        #pragma unroll
        for (int j = 0; j < 4; ++j) {
            const float inv = rsqrtf(ss[j]);
            union { __hip_bfloat16 h[4]; uint2 u; } p0, p1;
            p0.h[0] = __float2bfloat16(qa[j][0] * inv);
            p0.h[1] = __float2bfloat16(qa[j][1] * inv);
            p0.h[2] = __float2bfloat16(qa[j][2] * inv);
            p0.h[3] = __float2bfloat16(qa[j][3] * inv);
            p1.h[0] = __float2bfloat16(qc[j][0] * inv);
            p1.h[1] = __float2bfloat16(qc[j][1] * inv);
            p1.h[2] = __float2bfloat16(qc[j][2] * inv);
            p1.h[3] = __float2bfloat16(qc[j][3] * inv);
            uint2* dst = (uint2*)(qbo + (size_t)(r0 + j) * C_);
            dst[lane]      = p0.u;
            dst[64 + lane] = p1.u;
        }
    }

    __shared__ __align__(16) float red[4][C_];
    ((f32x4*)&red[wave][0])[lane]      = acca;
    ((f32x4*)&red[wave][0])[64 + lane] = accb;
    __syncthreads();
    for (int c = threadIdx.x; c < C_; c += 256) {
        float s = red[0][c] + red[1][c] + red[2][c] + red[3][c];
        atomicAdd(&kv[b * C_ + c], s);
    }
}

// ---------------- kernel 2: Wb[b][o][c] = bf16(kv[b][c] * W[o][c]) --------
__global__ __launch_bounds__(256)
void prep_w(const float* __restrict__ W, const float* __restrict__ kv,
            __hip_bfloat16* __restrict__ Wb) {
    int idx = blockIdx.x * 256 + threadIdx.x;
    int e   = idx << 2;
    int b   = e >> 18;
    int oc  = e & 0x3FFFF;
    int c   = oc & (C_ - 1);
    float4 w4 = *(const float4*)(W + oc);
    float4 s4 = *(const float4*)(kv + b * C_ + c);
    union { __hip_bfloat16 h[4]; uint2 u; } pk;
    pk.h[0] = __float2bfloat16(w4.x * s4.x);
    pk.h[1] = __float2bfloat16(w4.y * s4.y);
    pk.h[2] = __float2bfloat16(w4.z * s4.z);
    pk.h[3] = __float2bfloat16(w4.w * s4.w);
    *(uint2*)(Wb + e) = pk.u;
}

// ---------------- kernel 3: out = qb @ Wb^T + bias  (pure bf16 GEMM) ------
// BM=BN=256, BK=64, 512 thr = 8 waves (2M x 4N). r6 lesson: same geometry
// with __syncthreads (vmcnt(0) drain) per tile + 1 block/CU regressed vs
// 128^2 (90 vs 73 us) -- the drain was fully exposed. This round adds the
// missing T4: 2-deep prefetch + COUNTED vmcnt, never draining in-loop.
//   prologue: stage t0, t1            (16 gload_lds/wave in flight)
//   iter t:   vmcnt(8)  [tile t resident; t+1 stays in flight]
//             s_barrier
//             2 x {12 ds_read -> convoy s_barrier -> setprio(1) 32 MFMA}
//             s_barrier  [all waves done reading buf]
//             stage tile t+2 into the just-read buf   (t<6)
// Hazards: WAR on recycled buf closed by post-compute barrier; vmcnt
// in-order retirement => vmcnt(8) == oldest-8 (tile t) landed; all barriers
// wave-uniform. sched_barrier(0) pins issue order around asm waits.
__global__ __launch_bounds__(512, 2)
void gemm_out(const __hip_bfloat16* __restrict__ qbin, const __hip_bfloat16* __restrict__ Wb,
              const float* __restrict__ bias, float* __restrict__ out) {
    const int blk   = blockIdx.x;          // 512 blocks
    const int xcd   = blk & 7;
    const int local = blk >> 3;            // 0..63
    const int n0    = (local & 1) * 256;
    const int m0    = (xcd * 32 + (local >> 1)) * 256;
    const int b     = xcd;                 // == m0>>13 by construction
    const int tid   = threadIdx.x;
    const int lane  = tid & 63;
    const int wave  = tid >> 6;            // 0..7
    const int wn    = wave & 3;            // N-quadrant (64 cols)
    const int wm    = wave >> 2;           // M-half (128 rows)
    const int r16   = lane & 15;
    const int qd    = lane >> 4;

    __shared__ __align__(16) unsigned short As[2][256 * 64];   // 64 KB
    __shared__ __align__(16) unsigned short Bs[2][256 * 64];   // 64 KB

    const __hip_bfloat16* Abase = qbin + (size_t)m0 * C_;
    const __hip_bfloat16* Bbase = Wb + ((size_t)b * C_ + n0) * C_;

    f32x4 acc[8][4];
    #pragma unroll
    for (int i = 0; i < 8; ++i)
        #pragma unroll
        for (int j = 0; j < 4; ++j)
            acc[i][j] = (f32x4){0.f, 0.f, 0.f, 0.f};

    // stage one K-tile (A: 256x64, B: 256x64) -> 8 global_load_lds / thread.
    // Pre-swizzled global source + linear LDS dest. Swizzle: elem (r,k) at
    // r*64 + ((k>>3 ^ (r&7))<<3) + (k&7).   (layout verified passing r6)
    auto stage = [&](int buf, int kc) {
        #pragma unroll
        for (int i = 0; i < 4; ++i) {
            const int cb = (wave * 4 + i) * 64;        // chunk base
            const int r  = (cb >> 3) + (lane >> 3);    // row 0..255
            const int gk = (((lane & 7) ^ (r & 7)) << 3);
            __builtin_amdgcn_global_load_lds(GAS(Abase + (size_t)r * C_ + kc + gk),
                LAS(&As[buf][cb * 8]), 16, 0, 0);
            __builtin_amdgcn_global_load_lds(GAS(Bbase + (size_t)r * C_ + kc + gk),
                LAS(&Bs[buf][cb * 8]), 16, 0, 0);
        }
    };

    // one ks-phase: 12 ds_read_b128 -> convoy barrier -> 32 MFMA (setprio'd)
    auto phase = [&](int buf, int ks) {
        bf16x8 af[8], bfr[4];
        #pragma unroll
        for (int i = 0; i < 8; ++i) {
            const int row = wm * 128 + i * 16 + r16;
            af[i] = *(const bf16x8*)&As[buf][row * 64 + ((((ks << 2) | qd) ^ (row & 7)) << 3)];
        }
        #pragma unroll
        for (int j = 0; j < 4; ++j) {
            const int row = wn * 64 + j * 16 + r16;
            bfr[j] = *(const bf16x8*)&Bs[buf][row * 64 + ((((ks << 2) | qd) ^ (row & 7)) << 3)];
        }
        __builtin_amdgcn_sched_barrier(0);
        __builtin_amdgcn_s_barrier();
        __builtin_amdgcn_s_setprio(1);
        #pragma unroll
        for (int i = 0; i < 8; ++i)
            #pragma unroll
            for (int j = 0; j < 4; ++j)
                acc[i][j] = __builtin_amdgcn_mfma_f32_16x16x32_bf16(
                    af[i], bfr[j], acc[i][j], 0, 0, 0);
        __builtin_amdgcn_s_setprio(0);
        __builtin_amdgcn_sched_barrier(0);
    };

    // ---- prologue: 2-deep prefetch ----
    stage(0, 0);
    stage(1, 64);
    __builtin_amdgcn_sched_barrier(0);

    #pragma unroll 1
    for (int t = 0; t < 8; ++t) {
        const int cur = t & 1;
        if (t < 7) { asm volatile("s_waitcnt vmcnt(8)" ::: "memory"); }
        else       { asm volatile("s_waitcnt vmcnt(0)" ::: "memory"); }
        __builtin_amdgcn_sched_barrier(0);
        __builtin_amdgcn_s_barrier();          // tile t resident for ALL waves
        phase(cur, 0);
        phase(cur, 1);
        if (t < 6) {
            __builtin_amdgcn_s_barrier();      // all waves done reading buf cur
            __builtin_amdgcn_sched_barrier(0);
            stage(cur, (t + 2) * 64);          // recycle buf; stays in flight
            __builtin_amdgcn_sched_barrier(0);
        }
    }

    // ---- epilogue: add bias, store fp32 ----
    #pragma unroll
    for (int j = 0; j < 4; ++j) {
        const int col = n0 + wn * 64 + j * 16 + r16;
        const float bv = bias[col];
        #pragma unroll
        for (int i = 0; i < 8; ++i) {
            const int rl = m0 + wm * 128 + i * 16 + qd * 4;
            float* op = out + (size_t)rl * C_ + col;
            op[0]      = acc[i][j][0] + bv;
            op[C_]     = acc[i][j][1] + bv;
            op[2 * C_] = acc[i][j][2] + bv;
            op[3 * C_] = acc[i][j][3] + bv;
        }
    }
}

extern "C" void kernel_launch(void* const* d_in, const int* in_sizes, int n_in,
                              void* d_out, int out_size, void* d_ws, size_t ws_size,
                              hipStream_t stream) {
    const float* q    = (const float*)d_in[0];
    const float* k    = (const float*)d_in[1];
    const float* v    = (const float*)d_in[2];
    const float* W    = (const float*)d_in[3];
    const float* bias = (const float*)d_in[4];
    float* out = (float*)d_out;

    float* kv = (float*)d_ws;                                     // 16 KB
    __hip_bfloat16* Wb = (__hip_bfloat16*)((char*)d_ws + 16384);  // 4 MB
    __hip_bfloat16* qb = (__hip_bfloat16*)((char*)d_ws + 16384 + (size_t)B_ * C_ * C_ * 2); // 64 MB

    hipMemsetAsync(kv, 0, B_ * C_ * sizeof(float), stream);
    kv_qnorm<<<2048, 256, 0, stream>>>(k, v, q, kv, qb);
    prep_w<<<2048, 256, 0, stream>>>(W, kv, Wb);
    gemm_out<<<512, 512, 0, stream>>>(qb, Wb, bias, out);
}

// Round 8
// 417.402 us; speedup vs baseline: 1.0388x; 1.0388x over previous
//
#include <hip/hip_runtime.h>
#include <hip/hip_bf16.h>
#include <stdint.h>

#define B_ 8
#define L_ 8192
#define C_ 512

typedef short bf16x8 __attribute__((ext_vector_type(8)));
typedef float f32x4 __attribute__((ext_vector_type(4)));

#define GAS(p) ((const __attribute__((address_space(1))) void*)(p))
#define LAS(p) ((__attribute__((address_space(3))) void*)(p))

// ------- kernel 1: kv[b][c] = sum_l (k/||k||)*v   AND   qb = bf16(q/||q||) -------
// (unchanged from r4: ~89 us, ~5.2 TB/s effective; near streaming limit)
__global__ __launch_bounds__(256)
void kv_qnorm(const float* __restrict__ kin, const float* __restrict__ vin,
              const float* __restrict__ qin, float* __restrict__ kv,
              __hip_bfloat16* __restrict__ qb) {
    const int bi   = blockIdx.x;
    const int b    = bi >> 8;             // 256 blocks per batch
    const int row0 = (bi & 255) * 32;
    const int lane = threadIdx.x & 63;
    const int wave = threadIdx.x >> 6;

    const f32x4* kb = (const f32x4*)(kin + ((size_t)b * L_ + row0) * C_);
    const f32x4* vb = (const f32x4*)(vin + ((size_t)b * L_ + row0) * C_);

    f32x4 acca = {0.f,0.f,0.f,0.f}, accb = {0.f,0.f,0.f,0.f};

    #pragma unroll 1
    for (int it = 0; it < 2; ++it) {
        const int r0 = wave * 8 + it * 4;
        f32x4 ka[4], kc[4], va[4], vc[4];
        #pragma unroll
        for (int j = 0; j < 4; ++j) {
            const f32x4* krow = kb + (size_t)(r0 + j) * (C_/4);
            ka[j] = __builtin_nontemporal_load(krow + lane);
            kc[j] = __builtin_nontemporal_load(krow + 64 + lane);
        }
        #pragma unroll
        for (int j = 0; j < 4; ++j) {
            const f32x4* vrow = vb + (size_t)(r0 + j) * (C_/4);
            va[j] = __builtin_nontemporal_load(vrow + lane);
            vc[j] = __builtin_nontemporal_load(vrow + 64 + lane);
        }
        float ss[4];
        #pragma unroll
        for (int j = 0; j < 4; ++j)
            ss[j] = ka[j][0]*ka[j][0] + ka[j][1]*ka[j][1] + ka[j][2]*ka[j][2] + ka[j][3]*ka[j][3]
                  + kc[j][0]*kc[j][0] + kc[j][1]*kc[j][1] + kc[j][2]*kc[j][2] + kc[j][3]*kc[j][3];
        #pragma unroll
        for (int m = 32; m >= 1; m >>= 1) {
            #pragma unroll
            for (int j = 0; j < 4; ++j) ss[j] += __shfl_xor(ss[j], m);
        }
        #pragma unroll
        for (int j = 0; j < 4; ++j) {
            const float inv = rsqrtf(ss[j]);
            #pragma unroll
            for (int x = 0; x < 4; ++x) {
                acca[x] += ka[j][x] * inv * va[j][x];
                accb[x] += kc[j][x] * inv * vc[j][x];
            }
        }
    }

    const f32x4* qg = (const f32x4*)(qin + ((size_t)b * L_ + row0) * C_);
    __hip_bfloat16* qbo = qb + ((size_t)b * L_ + row0) * C_;
    #pragma unroll 1
    for (int it = 0; it < 2; ++it) {
        const int r0 = wave * 8 + it * 4;
        f32x4 qa[4], qc[4];
        #pragma unroll
        for (int j = 0; j < 4; ++j) {
            const f32x4* qrow = qg + (size_t)(r0 + j) * (C_/4);
            qa[j] = __builtin_nontemporal_load(qrow + lane);
            qc[j] = __builtin_nontemporal_load(qrow + 64 + lane);
        }
        float ss[4];
        #pragma unroll
        for (int j = 0; j < 4; ++j)
            ss[j] = qa[j][0]*qa[j][0] + qa[j][1]*qa[j][1] + qa[j][2]*qa[j][2] + qa[j][3]*qa[j][3]
                  + qc[j][0]*qc[j][0] + qc[j][1]*qc[j][1] + qc[j][2]*qc[j][2] + qc[j][3]*qc[j][3];
        #pragma unroll
        for (int m = 32; m >= 1; m >>= 1) {
            #pragma unroll
            for (int j = 0; j < 4; ++j) ss[j] += __shfl_xor(ss[j], m);
        }
        #pragma unroll
        for (int j = 0; j < 4; ++j) {
            const float inv = rsqrtf(ss[j]);
            union { __hip_bfloat16 h[4]; uint2 u; } p0, p1;
            p0.h[0] = __float2bfloat16(qa[j][0] * inv);
            p0.h[1] = __float2bfloat16(qa[j][1] * inv);
            p0.h[2] = __float2bfloat16(qa[j][2] * inv);
            p0.h[3] = __float2bfloat16(qa[j][3] * inv);
            p1.h[0] = __float2bfloat16(qc[j][0] * inv);
            p1.h[1] = __float2bfloat16(qc[j][1] * inv);
            p1.h[2] = __float2bfloat16(qc[j][2] * inv);
            p1.h[3] = __float2bfloat16(qc[j][3] * inv);
            uint2* dst = (uint2*)(qbo + (size_t)(r0 + j) * C_);
            dst[lane]      = p0.u;
            dst[64 + lane] = p1.u;
        }
    }

    __shared__ __align__(16) float red[4][C_];
    ((f32x4*)&red[wave][0])[lane]      = acca;
    ((f32x4*)&red[wave][0])[64 + lane] = accb;
    __syncthreads();
    for (int c = threadIdx.x; c < C_; c += 256) {
        float s = red[0][c] + red[1][c] + red[2][c] + red[3][c];
        atomicAdd(&kv[b * C_ + c], s);
    }
}

// ---------------- kernel 2: Wb[b][o][c] = bf16(kv[b][c] * W[o][c]) --------
__global__ __launch_bounds__(256)
void prep_w(const float* __restrict__ W, const float* __restrict__ kv,
            __hip_bfloat16* __restrict__ Wb) {
    int idx = blockIdx.x * 256 + threadIdx.x;
    int e   = idx << 2;
    int b   = e >> 18;
    int oc  = e & 0x3FFFF;
    int c   = oc & (C_ - 1);
    float4 w4 = *(const float4*)(W + oc);
    float4 s4 = *(const float4*)(kv + b * C_ + c);
    union { __hip_bfloat16 h[4]; uint2 u; } pk;
    pk.h[0] = __float2bfloat16(w4.x * s4.x);
    pk.h[1] = __float2bfloat16(w4.y * s4.y);
    pk.h[2] = __float2bfloat16(w4.z * s4.z);
    pk.h[3] = __float2bfloat16(w4.w * s4.w);
    *(uint2*)(Wb + e) = pk.u;
}

// ---------------- kernel 3: out = qb @ Wb^T + bias  (pure bf16 GEMM) ------
// REVERTED to the r4 structure (best measured: ~73 us): BM=BN=128, BK=64,
// 256 thr = 2x2 waves, double-buffered LDS (64 KB -> 2 blocks/CU), 1
// syncthreads per K-tile. r5-r7 taught: 256^2 (1 block/CU) loses the free
// cross-block wave overlap (m114) regardless of drain vs counted-vmcnt.
// ONE delta vs r4: nontemporal epilogue stores -- out is never re-read, and
// the 64B-segment column-group write pattern write-allocates L2/L3 lines
// for nothing (suspected source of r2's 72 MB gemm FETCH).
// LDS XOR-swizzle via pre-swizzled GLOBAL source + swizzled ds_read:
// elem (r,k) at r*64 + ((k>>3 ^ (r&7))<<3) + (k&7).
// XCD remap: 4 N-blocks of an M-panel on one XCD (r2: FETCH 267->72 MB).
__global__ __launch_bounds__(256, 2)
void gemm_out(const __hip_bfloat16* __restrict__ qbin, const __hip_bfloat16* __restrict__ Wb,
              const float* __restrict__ bias, float* __restrict__ out) {
    const int blk   = blockIdx.x;
    const int xcd   = blk & 7;
    const int local = blk >> 3;
    const int n0    = (local & 3) * 128;
    const int m0    = (xcd * 64 + (local >> 2)) * 128;
    const int b     = m0 >> 13;
    const int tid  = threadIdx.x;
    const int lane = tid & 63;
    const int wave = tid >> 6;

    __shared__ __align__(16) unsigned short As[2][128 * 64];
    __shared__ __align__(16) unsigned short Bs[2][128 * 64];

    const __hip_bfloat16* Abase = qbin + (size_t)m0 * C_;
    const __hip_bfloat16* Bbase = Wb + ((size_t)b * C_ + n0) * C_;

    const int r16 = lane & 15;
    const int qd  = lane >> 4;
    const int wm  = wave & 1;
    const int wn  = wave >> 1;

    f32x4 acc[4][4];
    #pragma unroll
    for (int i = 0; i < 4; ++i)
        #pragma unroll
        for (int j = 0; j < 4; ++j)
            acc[i][j] = (f32x4){0.f, 0.f, 0.f, 0.f};

    auto stage = [&](int buf, int kc) {
        #pragma unroll
        for (int i = 0; i < 4; ++i) {
            int cid = i * 256 + wave * 64 + lane;     // 16B chunk id, 0..1023
            int r   = cid >> 3;                        // tile row
            int cj  = cid & 7;                         // k-chunk within row
            int kk  = ((cj ^ (r & 7)) << 3);           // pre-swizzled source col
            __builtin_amdgcn_global_load_lds(GAS(Abase + (size_t)r * C_ + kc + kk),
                LAS(&As[buf][(i * 256 + wave * 64) * 8]), 16, 0, 0);
            __builtin_amdgcn_global_load_lds(GAS(Bbase + (size_t)r * C_ + kc + kk),
                LAS(&Bs[buf][(i * 256 + wave * 64) * 8]), 16, 0, 0);
        }
    };
    auto compute = [&](int buf) {
        #pragma unroll
        for (int ks = 0; ks < 2; ++ks) {
            bf16x8 af[4], bfr[4];
            #pragma unroll
            for (int t = 0; t < 4; ++t) {
                int m = wm * 64 + t * 16 + r16;
                af[t]  = *(const bf16x8*)&As[buf][m * 64 + (((ks * 4 + qd) ^ (m & 7)) << 3)];
                int n = wn * 64 + t * 16 + r16;
                bfr[t] = *(const bf16x8*)&Bs[buf][n * 64 + (((ks * 4 + qd) ^ (n & 7)) << 3)];
            }
            #pragma unroll
            for (int mt = 0; mt < 4; ++mt)
                #pragma unroll
                for (int nt = 0; nt < 4; ++nt)
                    acc[mt][nt] = __builtin_amdgcn_mfma_f32_16x16x32_bf16(
                        af[mt], bfr[nt], acc[mt][nt], 0, 0, 0);
        }
    };

    stage(0, 0);
    __syncthreads();                 // tile 0 resident (vmcnt drain)
    #pragma unroll
    for (int t = 0; t < 7; ++t) {
        stage((t & 1) ^ 1, (t + 1) * 64);   // next tile in flight across MFMAs
        compute(t & 1);
        __syncthreads();             // cur reads done + next tile landed
    }
    compute(1);

    // ---- epilogue: add bias, nontemporal fp32 store (out never re-read) ----
    #pragma unroll
    for (int nt = 0; nt < 4; ++nt) {
        int col  = n0 + wn * 64 + nt * 16 + r16;
        float bv = bias[col];
        #pragma unroll
        for (int mt = 0; mt < 4; ++mt) {
            int rl = wm * 64 + mt * 16 + qd * 4;
            float* op = out + (size_t)(m0 + rl) * C_ + col;
            __builtin_nontemporal_store(acc[mt][nt][0] + bv, op);
            __builtin_nontemporal_store(acc[mt][nt][1] + bv, op + C_);
            __builtin_nontemporal_store(acc[mt][nt][2] + bv, op + 2 * C_);
            __builtin_nontemporal_store(acc[mt][nt][3] + bv, op + 3 * C_);
        }
    }
}

extern "C" void kernel_launch(void* const* d_in, const int* in_sizes, int n_in,
                              void* d_out, int out_size, void* d_ws, size_t ws_size,
                              hipStream_t stream) {
    const float* q    = (const float*)d_in[0];
    const float* k    = (const float*)d_in[1];
    const float* v    = (const float*)d_in[2];
    const float* W    = (const float*)d_in[3];
    const float* bias = (const float*)d_in[4];
    float* out = (float*)d_out;

    float* kv = (float*)d_ws;                                     // 16 KB
    __hip_bfloat16* Wb = (__hip_bfloat16*)((char*)d_ws + 16384);  // 4 MB
    __hip_bfloat16* qb = (__hip_bfloat16*)((char*)d_ws + 16384 + (size_t)B_ * C_ * C_ * 2); // 64 MB

    hipMemsetAsync(kv, 0, B_ * C_ * sizeof(float), stream);
    kv_qnorm<<<2048, 256, 0, stream>>>(k, v, q, kv, qb);
    prep_w<<<2048, 256, 0, stream>>>(W, kv, Wb);
    gemm_out<<<2048, 256, 0, stream>>>(qb, Wb, bias, out);
}